// Round 2
// baseline (960.159 us; speedup 1.0000x reference)
//
#include <hip/hip_runtime.h>
#include <math.h>

// Problem constants
#define BB 8
#define NN 512
#define DD 256
#define BN (BB*NN)   // 4096

// Workspace layout (float offsets). Total ~11.2M floats = 44.7 MB.
#define OFF_S0   0u         // symbols0            [4096][256]
#define OFF_ASUM 1048576u   // per-batch sums      [8][256]
#define OFF_S    1050624u   // S rows              [4096][1536]  (S_0..S_4, Stot)
#define OFF_CNT  7342080u   // counts (float)      [4096][8]     (r=0..4 used)
#define OFF_WCAT 7374848u   // Wcat                [1536][256]   (W_r - W_5 ; W_5)
#define OFF_RB   7768064u   // rbcat               [6][256]      (b_r - b_5 ; 511*b_5)
#define OFF_WBIG 7769600u   // Wbig                [256][1024]   (h1W0|h1W1|h1W2|outW)
#define OFF_BBIG 8031744u   // bbig                [1024]        (h1b0|h1b1|h1b2|outb)
#define OFF_H    8032768u   // gelu activations    [4096][768]

// d_out layout (floats)
#define OUT0_OFF   0u        // output  [8][512][256]
#define INTERP_OFF 1048576u  // interp  [3][4096]  (exoteric, esoteric, sacred)
#define SYM_OFF    1060864u  // symbols [8][512][256]

__device__ __forceinline__ float gelu_exact(float x) {
    return 0.5f * x * (1.0f + erff(x * 0.70710678118654752f));
}

// ---------------------------------------------------------------- prep ----
__global__ __launch_bounds__(256) void prep_kernel(
    const float* __restrict__ relW, const float* __restrict__ relb,
    const float* __restrict__ h1W,  const float* __restrict__ h1b,
    const float* __restrict__ outW, const float* __restrict__ outb,
    float* __restrict__ ws)
{
    int idx = blockIdx.x * 256 + threadIdx.x;   // grid covers 393216
    // Wcat [1536][256]: rows r*256+d ; r<5 -> W_r - W_5 ; r==5 -> W_5
    {
        int row = idx >> 8, col = idx & 255;
        int r = row >> 8, d = row & 255;
        float w5 = relW[(5 * DD + d) * DD + col];
        ws[OFF_WCAT + idx] = (r < 5) ? (relW[(r * DD + d) * DD + col] - w5) : w5;
    }
    // Wbig [256][1024]
    if (idx < 262144) {
        int d = idx >> 10, c = idx & 1023;
        float v;
        if (c < 768) { int r = c >> 8, e = c & 255; v = h1W[(r * DD + d) * DD + e]; }
        else         { v = outW[d * DD + (c - 768)]; }
        ws[OFF_WBIG + idx] = v;
    }
    // rbcat [6][256]
    if (idx < 1536) {
        int r = idx >> 8, col = idx & 255;
        float b5 = relb[5 * DD + col];
        ws[OFF_RB + idx] = (r < 5) ? (relb[r * DD + col] - b5) : (float)(NN - 1) * b5;
    }
    // bbig [1024]
    if (idx < 1024) {
        ws[OFF_BBIG + idx] = (idx < 768) ? h1b[idx] : outb[idx - 768];
    }
}

// -------------------------------------------------------------- gather ----
__global__ __launch_bounds__(256) void gather_kernel(
    const int* __restrict__ ids, const float* __restrict__ symt,
    const float* __restrict__ layt, float* __restrict__ s0)
{
    int idx = blockIdx.x * 256 + threadIdx.x;   // 1048576 total
    int row = idx >> 8, c = idx & 255;
    int id = ids[row];
    s0[idx] = symt[id * DD + c] + layt[id * DD + c];
}

// ------------------------------------------------------------ batchsum ----
__global__ __launch_bounds__(1024) void batchsum_kernel(
    const float* __restrict__ s0, float* __restrict__ Asum)
{
    int b = blockIdx.x;
    int e = threadIdx.x & 255, c = threadIdx.x >> 8;   // 4-way i split
    __shared__ float red[1024];
    float s = 0.f;
    for (int n = c * 128; n < c * 128 + 128; n++)
        s += s0[((size_t)b * NN + n) * DD + e];
    red[threadIdx.x] = s;
    __syncthreads();
    if (threadIdx.x < 256)
        Asum[b * DD + e] = red[e] + red[256 + e] + red[512 + e] + red[768 + e];
}

// --------------------------------------------------------- grammar agg ----
// Block = (b, tile of 8 j's). 256 threads: dgrp = t&63 -> d = dgrp*4 (float4),
// tj = t>>6 -> owns j0+tj and j0+tj+4. Relation codes are wave-uniform; the
// dominant input pattern (all pairs class 4) takes a single scalar compare
// fast path of 8 v_adds. Manual double-buffered prefetch of 8 rows keeps
// 8 loads in flight across the branchy section.
__global__ __launch_bounds__(256) void grammar_agg(
    const float* __restrict__ positions, const float* __restrict__ s0,
    const float* __restrict__ Asum, float* __restrict__ Sws, float* __restrict__ cntws)
{
    int blk = blockIdx.x;            // 512 = 8 b * 64 jtiles
    int b = blk >> 6;
    int j0 = (blk & 63) << 3;
    int tid = threadIdx.x;
    __shared__ float px[NN], py[NN];
    __shared__ unsigned int relp[NN];
    __shared__ int cnts[8 * 5];

    for (int i = tid; i < NN; i += 256) {
        float2 p = ((const float2*)positions)[b * NN + i];
        px[i] = p.x; py[i] = p.y;
    }
    if (tid < 40) cnts[tid] = 0;
    __syncthreads();

    float xj[8], yj[8];
#pragma unroll
    for (int t = 0; t < 8; t++) { xj[t] = px[j0 + t]; yj[t] = py[j0 + t]; }

    // classify: rel[b,i,j], self forced to class 5 (handled by Stot path)
    for (int i = tid; i < NN; i += 256) {
        float xi = px[i], yi = py[i];
        unsigned int pk = 0;
#pragma unroll
        for (int t = 0; t < 8; t++) {
            float dx = xj[t] - xi, dy = yj[t] - yi;
            int r;
            if      (dy >  0.5f) r = 0;
            else if (dy < -0.5f) r = 1;
            else if (dx < -0.5f) r = 2;
            else if (dx >  0.5f) r = 3;
            else if (fabsf(dx) < 0.3f && fabsf(dy) < 0.3f) r = 4;
            else r = 5;
            if (i == j0 + t) r = 5;          // exclude self
            if (r < 5) atomicAdd(&cnts[t * 5 + r], 1);
            pk |= (unsigned)r << (3 * t);
        }
        relp[i] = pk;
    }
    __syncthreads();

    int dgrp = tid & 63;             // d = dgrp*4
    int tj = tid >> 6;               // owns j0+tj, j0+tj+4
    int sh_a = 3 * tj, sh_b = 3 * (tj + 4);

    float acc[5][2][4];
#pragma unroll
    for (int r = 0; r < 5; r++)
#pragma unroll
        for (int q = 0; q < 2; q++)
#pragma unroll
            for (int c = 0; c < 4; c++) acc[r][q][c] = 0.f;

    const float4* srow = (const float4*)(s0 + (size_t)b * NN * DD) + dgrp;

    float4 sv[2][8];
#pragma unroll
    for (int u = 0; u < 8; u++) sv[0][u] = srow[(size_t)u * 64];

#define PROCESS(gg, buf)                                                     \
    {                                                                        \
        _Pragma("unroll")                                                    \
        for (int u = 0; u < 8; u++) {                                        \
            unsigned int pk = (unsigned)__builtin_amdgcn_readfirstlane(      \
                (int)relp[(gg) * 8 + u]);                                    \
            float4 s = (buf)[u];                                             \
            if (pk == 0x924924u) {                                           \
                acc[4][0][0] += s.x; acc[4][0][1] += s.y;                    \
                acc[4][0][2] += s.z; acc[4][0][3] += s.w;                    \
                acc[4][1][0] += s.x; acc[4][1][1] += s.y;                    \
                acc[4][1][2] += s.z; acc[4][1][3] += s.w;                    \
            } else {                                                         \
                unsigned int r0 = (pk >> sh_a) & 7u;                         \
                if (r0 < 5u) {                                               \
                    acc[r0][0][0] += s.x; acc[r0][0][1] += s.y;              \
                    acc[r0][0][2] += s.z; acc[r0][0][3] += s.w;              \
                }                                                            \
                unsigned int r1 = (pk >> sh_b) & 7u;                         \
                if (r1 < 5u) {                                               \
                    acc[r1][1][0] += s.x; acc[r1][1][1] += s.y;              \
                    acc[r1][1][2] += s.z; acc[r1][1][3] += s.w;              \
                }                                                            \
            }                                                                \
        }                                                                    \
    }

    for (int g = 0; g < 63; g++) {
        float4* nxt = sv[(g + 1) & 1];
#pragma unroll
        for (int u = 0; u < 8; u++) nxt[u] = srow[(size_t)((g + 1) * 8 + u) * 64];
        PROCESS(g, sv[g & 1]);
    }
    PROCESS(63, sv[63 & 1]);
#undef PROCESS

    int d = dgrp * 4;
    float4 a4 = *(const float4*)&Asum[b * DD + d];
#pragma unroll
    for (int q = 0; q < 2; q++) {
        int j = j0 + tj + q * 4;
        size_t base = (size_t)(b * NN + j) * (6 * DD);
#pragma unroll
        for (int r = 0; r < 5; r++) {
            float4 v; v.x = acc[r][q][0]; v.y = acc[r][q][1];
            v.z = acc[r][q][2]; v.w = acc[r][q][3];
            *(float4*)&Sws[base + r * DD + d] = v;
        }
        float4 s0j = *(const float4*)&s0[((size_t)b * NN + j) * DD + d];
        float4 st; st.x = a4.x - s0j.x; st.y = a4.y - s0j.y;
        st.z = a4.z - s0j.z; st.w = a4.w - s0j.w;
        *(float4*)&Sws[base + 5 * DD + d] = st;
    }
    if (tid < 40) {
        int t = tid / 5, r = tid % 5;
        cntws[(size_t)(b * NN + j0 + t) * 8 + r] = (float)cnts[t * 5 + r];
    }
}

// ----------------------------------------------------------------- gemm1 --
// symbols_final[4096][256] = Sws[4096][1536] @ Wcat[1536][256] + s0 + bias
__global__ __launch_bounds__(256) void gemm1_kernel(
    const float* __restrict__ Aw, const float* __restrict__ Wc,
    const float* __restrict__ s0, const float* __restrict__ cnt,
    const float* __restrict__ rbcat, float* __restrict__ symout)
{
    const int K = 1536;
    __shared__ float As[16][68];
    __shared__ float Ws[16][68];
    int tid = threadIdx.x;
    int tx = tid & 15, ty = tid >> 4;
    int row0 = blockIdx.y * 64, col0 = blockIdx.x * 64;
    int lr = tid >> 2, lk = tid & 3;
    int lwk = tid >> 4, lwc = tid & 15;
    float acc[4][4] = {};

    for (int k0 = 0; k0 < K; k0 += 16) {
        float4 a = *(const float4*)&Aw[(size_t)(row0 + lr) * K + k0 + lk * 4];
        float4 w = *(const float4*)&Wc[(size_t)(k0 + lwk) * DD + col0 + lwc * 4];
        __syncthreads();
        As[lk * 4 + 0][lr] = a.x; As[lk * 4 + 1][lr] = a.y;
        As[lk * 4 + 2][lr] = a.z; As[lk * 4 + 3][lr] = a.w;
        *(float4*)&Ws[lwk][lwc * 4] = w;
        __syncthreads();
#pragma unroll
        for (int kk = 0; kk < 16; kk++) {
            float av[4], wv[4];
            *(float4*)av = *(const float4*)&As[kk][ty * 4];
            *(float4*)wv = *(const float4*)&Ws[kk][tx * 4];
#pragma unroll
            for (int i2 = 0; i2 < 4; i2++)
#pragma unroll
                for (int j2 = 0; j2 < 4; j2++) acc[i2][j2] += av[i2] * wv[j2];
        }
    }
    // epilogue: + symbols0 + count-weighted relation bias
    int colb = col0 + tx * 4;
    float rbv[6][4];
#pragma unroll
    for (int r = 0; r < 6; r++)
#pragma unroll
        for (int j2 = 0; j2 < 4; j2++) rbv[r][j2] = rbcat[r * DD + colb + j2];
#pragma unroll
    for (int i2 = 0; i2 < 4; i2++) {
        int row = row0 + ty * 4 + i2;
        float c5[5];
#pragma unroll
        for (int r = 0; r < 5; r++) c5[r] = cnt[(size_t)row * 8 + r];
#pragma unroll
        for (int j2 = 0; j2 < 4; j2++) {
            float v = acc[i2][j2] + s0[(size_t)row * DD + colb + j2] + rbv[5][j2];
#pragma unroll
            for (int r = 0; r < 5; r++) v += c5[r] * rbv[r][j2];
            symout[(size_t)row * DD + colb + j2] = v;
        }
    }
}

// ----------------------------------------------------------------- gemm2 --
// [4096][256] @ Wbig[256][1024]; cols<768 -> gelu -> Hws; cols>=768 -> out0
__global__ __launch_bounds__(256) void gemm2_kernel(
    const float* __restrict__ Aw, const float* __restrict__ Wb,
    const float* __restrict__ bbig, float* __restrict__ Hws, float* __restrict__ out0)
{
    const int K = 256, NC = 1024;
    __shared__ float As[16][68];
    __shared__ float Ws[16][68];
    int tid = threadIdx.x;
    int tx = tid & 15, ty = tid >> 4;
    int row0 = blockIdx.y * 64, col0 = blockIdx.x * 64;
    int lr = tid >> 2, lk = tid & 3;
    int lwk = tid >> 4, lwc = tid & 15;
    float acc[4][4] = {};

    for (int k0 = 0; k0 < K; k0 += 16) {
        float4 a = *(const float4*)&Aw[(size_t)(row0 + lr) * K + k0 + lk * 4];
        float4 w = *(const float4*)&Wb[(size_t)(k0 + lwk) * NC + col0 + lwc * 4];
        __syncthreads();
        As[lk * 4 + 0][lr] = a.x; As[lk * 4 + 1][lr] = a.y;
        As[lk * 4 + 2][lr] = a.z; As[lk * 4 + 3][lr] = a.w;
        *(float4*)&Ws[lwk][lwc * 4] = w;
        __syncthreads();
#pragma unroll
        for (int kk = 0; kk < 16; kk++) {
            float av[4], wv[4];
            *(float4*)av = *(const float4*)&As[kk][ty * 4];
            *(float4*)wv = *(const float4*)&Ws[kk][tx * 4];
#pragma unroll
            for (int i2 = 0; i2 < 4; i2++)
#pragma unroll
                for (int j2 = 0; j2 < 4; j2++) acc[i2][j2] += av[i2] * wv[j2];
        }
    }
    int colb = col0 + tx * 4;
#pragma unroll
    for (int i2 = 0; i2 < 4; i2++) {
        int row = row0 + ty * 4 + i2;
#pragma unroll
        for (int j2 = 0; j2 < 4; j2++) {
            int c = colb + j2;
            float v = acc[i2][j2] + bbig[c];
            if (col0 < 768) Hws[(size_t)row * 768 + c] = gelu_exact(v);
            else            out0[(size_t)row * DD + (c - 768)] = v;
        }
    }
}

// ---------------------------------------------------------------- interp --
// interp[r][bn] = sum_e Hws[bn][r*256+e] * h2W[r][e] + h2b[r]
__global__ __launch_bounds__(256) void interp_kernel(
    const float* __restrict__ Hws, const float* __restrict__ h2W,
    const float* __restrict__ h2b, float* __restrict__ outI)
{
    int wave = threadIdx.x >> 6, lane = threadIdx.x & 63;
    int bn = blockIdx.x * 4 + wave;
#pragma unroll
    for (int r = 0; r < 3; r++) {
        float s = 0.f;
#pragma unroll
        for (int q = 0; q < 4; q++) {
            int e = lane + 64 * q;
            s += Hws[(size_t)bn * 768 + r * 256 + e] * h2W[r * 256 + e];
        }
        for (int off = 32; off > 0; off >>= 1) s += __shfl_down(s, off);
        if (lane == 0) outI[r * BN + bn] = s + h2b[r];
    }
}

// ---------------------------------------------------------------- launch --
extern "C" void kernel_launch(void* const* d_in, const int* in_sizes, int n_in,
                              void* d_out, int out_size, void* d_ws, size_t ws_size,
                              hipStream_t stream)
{
    const int*   ids  = (const int*)d_in[0];
    const float* pos  = (const float*)d_in[1];
    const float* symt = (const float*)d_in[2];
    const float* layt = (const float*)d_in[3];
    const float* relW = (const float*)d_in[4];
    const float* relb = (const float*)d_in[5];
    const float* h1W  = (const float*)d_in[6];
    const float* h1b  = (const float*)d_in[7];
    const float* h2W  = (const float*)d_in[8];
    const float* h2b  = (const float*)d_in[9];
    const float* outW = (const float*)d_in[10];
    const float* outb = (const float*)d_in[11];
    float* out = (float*)d_out;
    float* ws  = (float*)d_ws;

    prep_kernel<<<1536, 256, 0, stream>>>(relW, relb, h1W, h1b, outW, outb, ws);
    gather_kernel<<<4096, 256, 0, stream>>>(ids, symt, layt, ws + OFF_S0);
    batchsum_kernel<<<BB, 1024, 0, stream>>>(ws + OFF_S0, ws + OFF_ASUM);
    grammar_agg<<<512, 256, 0, stream>>>(pos, ws + OFF_S0, ws + OFF_ASUM,
                                         ws + OFF_S, ws + OFF_CNT);
    gemm1_kernel<<<dim3(4, 64), 256, 0, stream>>>(ws + OFF_S, ws + OFF_WCAT,
                                                  ws + OFF_S0, ws + OFF_CNT,
                                                  ws + OFF_RB, out + SYM_OFF);
    gemm2_kernel<<<dim3(16, 64), 256, 0, stream>>>(out + SYM_OFF, ws + OFF_WBIG,
                                                   ws + OFF_BBIG, ws + OFF_H, out + OUT0_OFF);
    interp_kernel<<<1024, 256, 0, stream>>>(ws + OFF_H, h2W, h2b, out + INTERP_OFF);
}

// Round 4
// 227.674 us; speedup vs baseline: 4.2173x; 4.2173x over previous
//
#include <hip/hip_runtime.h>
#include <hip/hip_bf16.h>
#include <math.h>

#define BB 8
#define NN 512
#define DD 256
#define BNT 4096   // B*N

typedef __attribute__((ext_vector_type(8))) short short8;
typedef __attribute__((ext_vector_type(4))) float f32x4;

// Workspace layout (float offsets). Peak ~45.5 MB.
#define OFF_S0    0u          // fp32 [4096][256]                 s0
#define OFF_S0T   1048576u    // bf16 [8][256][512]               s0 transposed per batch
#define OFF_MASK  1572864u    // bf16 [8][6][512][512]            relation masks (dead after agg)
#define OFF_SYMH  1572864u    // bf16 [4096][256]  OVERLAPS MASK  (written by gemm1, after agg)
#define OFF_SA    7864320u    // bf16 [4096][1536]                aggregated S (r-major cols)
#define OFF_CNT   11010048u   // int  [4096][8]                   relation counts per (b,j)
#define OFF_WCT   11042816u   // bf16 [256][1536]                 Wcat^T  (e rows, k=(r,d))
#define OFF_WBT   11239424u   // bf16 [1024][256]                 Wbig^T  (c rows, k=d)
#define OFF_BB    11370496u   // fp32 [1024]                      h1b|outb

// d_out layout (floats)
#define OUT0_OFF   0u        // output  [8][512][256]
#define INTERP_OFF 1048576u  // interp  [3][4096]
#define SYM_OFF    1060864u  // symbols [8][512][256]

__device__ __forceinline__ float gelu_exact(float x) {
    return 0.5f * x * (1.0f + erff(x * 0.70710678118654752f));
}

// ================= shared MFMA core: 128x128 tile, BK=32, 4 waves 2x2 =====
// A [M][K] row-major bf16 (k-contiguous), B stored transposed [N][K] bf16.
// LDS layout: 16B chunks indexed [quad(k/8)][row] -> conflict-free b128.
// Fragment layouts (verified m89/m91/m120): A: m=lane&15, k=quad*8+j;
// B: n=lane&15, k=quad*8+j; C/D: col=lane&15, row=quad*4+reg.
__device__ __forceinline__ void gemm_core(
    const ushort* __restrict__ Ag, int lda,
    const ushort* __restrict__ Bg, int ldb, int K,
    int row0, int col0, int tid,
    ushort* Als, ushort* Bls, f32x4 acc[4][4])
{
    const int lane = tid & 63, w = tid >> 6;
    const int wm = w >> 1, wn = w & 1;
    const int quad = lane >> 4, l15 = lane & 15;
    const int sm = tid >> 1;           // staged row 0..127
    const int sq = (tid & 1) * 2;      // chunk pair 0 or 2
    const ushort* gA = Ag + (size_t)(row0 + sm) * lda + sq * 8;
    const ushort* gB = Bg + (size_t)(col0 + sm) * ldb + sq * 8;

    for (int k0 = 0; k0 < K; k0 += 32) {
        uint4 a0 = *(const uint4*)(gA + k0);
        uint4 a1 = *(const uint4*)(gA + k0 + 8);
        uint4 b0 = *(const uint4*)(gB + k0);
        uint4 b1 = *(const uint4*)(gB + k0 + 8);
        __syncthreads();
        *(uint4*)&Als[(sq * 128 + sm) * 8]       = a0;
        *(uint4*)&Als[((sq + 1) * 128 + sm) * 8] = a1;
        *(uint4*)&Bls[(sq * 128 + sm) * 8]       = b0;
        *(uint4*)&Bls[((sq + 1) * 128 + sm) * 8] = b1;
        __syncthreads();
        short8 af[4], bf[4];
#pragma unroll
        for (int mt = 0; mt < 4; mt++)
            af[mt] = *(const short8*)&Als[(quad * 128 + wm * 64 + mt * 16 + l15) * 8];
#pragma unroll
        for (int nt = 0; nt < 4; nt++)
            bf[nt] = *(const short8*)&Bls[(quad * 128 + wn * 64 + nt * 16 + l15) * 8];
#pragma unroll
        for (int mt = 0; mt < 4; mt++)
#pragma unroll
            for (int nt = 0; nt < 4; nt++)
                acc[mt][nt] = __builtin_amdgcn_mfma_f32_16x16x32_bf16(
                    af[mt], bf[nt], acc[mt][nt], 0, 0, 0);
    }
}

#define GEMM_PROLOGUE()                                        \
    __shared__ ushort Als[4096], Bls[4096];                    \
    int tid = threadIdx.x;                                     \
    f32x4 acc[4][4];                                           \
    _Pragma("unroll") for (int mt = 0; mt < 4; mt++)           \
    _Pragma("unroll") for (int nt = 0; nt < 4; nt++)           \
        acc[mt][nt] = (f32x4){0.f, 0.f, 0.f, 0.f};

#define EPI_IDS()                                              \
    int lane = tid & 63, w = tid >> 6;                         \
    int wm = w >> 1, wn = w & 1;                               \
    int quad = lane >> 4, l15 = lane & 15;

// ---------------------------------------------------------------- prep ----
// WcT[e][r*256+d] = relW[r][d][e]; WbT[c][d] = h1W/outW; bbig = h1b|outb
__global__ __launch_bounds__(256) void prep_kernel(
    const float* __restrict__ relW, const float* __restrict__ h1W,
    const float* __restrict__ outW, const float* __restrict__ h1b,
    const float* __restrict__ outb,
    __hip_bfloat16* __restrict__ WcT, __hip_bfloat16* __restrict__ WbT,
    float* __restrict__ bbig)
{
    int idx = blockIdx.x * 256 + threadIdx.x;    // grid 1536 -> 393216
    {
        int e = idx / 1536, k = idx - e * 1536;
        int r = k >> 8, d = k & 255;
        WcT[idx] = __float2bfloat16(relW[(r * DD + d) * DD + e]);
    }
    if (idx < 262144) {
        int c = idx >> 8, d = idx & 255;
        float v;
        if (c < 768) { int r = c >> 8, e = c & 255; v = h1W[(r * DD + d) * DD + e]; }
        else         { v = outW[d * DD + (c - 768)]; }
        WbT[idx] = __float2bfloat16(v);
    }
    if (idx < 1024) bbig[idx] = (idx < 768) ? h1b[idx] : outb[idx - 768];
}

// -------------------------------------------------------------- gather ----
__global__ __launch_bounds__(256) void gather_kernel(
    const int* __restrict__ ids, const float* __restrict__ symt,
    const float* __restrict__ layt, float* __restrict__ s0)
{
    int idx = blockIdx.x * 256 + threadIdx.x;   // 1048576
    int row = idx >> 8, c = idx & 255;
    int id = ids[row];
    s0[idx] = symt[id * DD + c] + layt[id * DD + c];
}

// ----------------------------------------------------------- transpose ----
// s0T[b][d][i] = bf16(s0[b][i][d]); 64x64 LDS tiles.
__global__ __launch_bounds__(256) void transpose_kernel(
    const float* __restrict__ s0, __hip_bfloat16* __restrict__ s0T)
{
    __shared__ float tile[64][65];
    int b = blockIdx.z, i0 = blockIdx.x * 64, d0 = blockIdx.y * 64;
    int x = threadIdx.x & 63, g = threadIdx.x >> 6;
#pragma unroll
    for (int k = 0; k < 16; k++) {
        int il = g * 16 + k;
        tile[il][x] = s0[((size_t)(b * NN) + i0 + il) * DD + d0 + x];
    }
    __syncthreads();
#pragma unroll
    for (int k = 0; k < 16; k++) {
        int dl = g * 16 + k;
        s0T[((size_t)(b * DD) + d0 + dl) * NN + i0 + x] = __float2bfloat16(tile[x][dl]);
    }
}

// -------------------------------------------------------------- classify --
// Writes bf16 one-hot masks Mt[b][r][j][i] (self-pairs -> all-zero) and
// exact int counts cnt[b*512+j][r].
__global__ __launch_bounds__(256) void classify_kernel(
    const float* __restrict__ positions, ushort* __restrict__ mask,
    int* __restrict__ cnt)
{
    int b = blockIdx.x >> 3;
    int jt = blockIdx.x & 7;
    int tid = threadIdx.x, lane = tid & 63, w = tid >> 6;
    __shared__ float px[NN], py[NN];
    for (int i = tid; i < NN; i += 256) {
        float2 p = ((const float2*)positions)[b * NN + i];
        px[i] = p.x; py[i] = p.y;
    }
    __syncthreads();
    for (int jj = 0; jj < 16; jj++) {
        int j = jt * 64 + w * 16 + jj;
        float xj = px[j], yj = py[j];
        int c[6] = {0, 0, 0, 0, 0, 0};
        for (int it = 0; it < 8; it++) {
            int i = it * 64 + lane;
            float dx = xj - px[i], dy = yj - py[i];
            int r;
            if      (dy >  0.5f) r = 0;
            else if (dy < -0.5f) r = 1;
            else if (dx < -0.5f) r = 2;
            else if (dx >  0.5f) r = 3;
            else if (fabsf(dx) < 0.3f && fabsf(dy) < 0.3f) r = 4;
            else r = 5;
            if (i == j) r = 6;                  // self: no mask, no count
            size_t base = ((size_t)(b * 6) * NN + j) * NN + i;
#pragma unroll
            for (int rr = 0; rr < 6; rr++) {
                mask[base + (size_t)rr * NN * NN] = (r == rr) ? 0x3F80 : 0;
                c[rr] += (r == rr) ? 1 : 0;
            }
        }
#pragma unroll
        for (int rr = 0; rr < 6; rr++) {
            int v = c[rr];
            v += __shfl_xor(v, 32); v += __shfl_xor(v, 16);
            v += __shfl_xor(v, 8);  v += __shfl_xor(v, 4);
            v += __shfl_xor(v, 2);  v += __shfl_xor(v, 1);
            if (lane == 0) cnt[(b * NN + j) * 8 + rr] = v;
        }
    }
}

// ---------------------------------------------------------- init interp ---
__global__ __launch_bounds__(256) void init_interp_kernel(
    const float* __restrict__ h2b, float* __restrict__ outI)
{
    int idx = blockIdx.x * 256 + threadIdx.x;   // 12288
    if (idx < 3 * BNT) outI[idx] = h2b[idx >> 12];
}

// ------------------------------------------------------------- agg gemm ---
// SA[b*512+j][r*256+d] = sum_i Mt[b,r][j][i] * s0[b][i][d]
__global__ __launch_bounds__(256) void agg_gemm(
    const ushort* __restrict__ mask, const ushort* __restrict__ s0T,
    __hip_bfloat16* __restrict__ SA)
{
    GEMM_PROLOGUE();
    int z = blockIdx.z, b = z / 6, r = z - b * 6;
    int row0 = blockIdx.y * 128, col0 = blockIdx.x * 128;
    gemm_core(mask + (size_t)z * NN * NN, NN,
              s0T + (size_t)b * DD * NN, NN, NN,
              row0, col0, tid, Als, Bls, acc);
    EPI_IDS();
#pragma unroll
    for (int mt = 0; mt < 4; mt++)
#pragma unroll
        for (int nt = 0; nt < 4; nt++)
#pragma unroll
            for (int v = 0; v < 4; v++) {
                int row = row0 + wm * 64 + mt * 16 + quad * 4 + v;
                int col = col0 + wn * 64 + nt * 16 + l15;
                SA[(size_t)(b * NN + row) * 1536 + r * DD + col] =
                    __float2bfloat16(acc[mt][nt][v]);
            }
}

// ----------------------------------------------------------------- gemm1 --
// symbols = SA @ Wcat + s0 + sum_r cnt_r * relb_r ; also bf16 copy symH
__global__ __launch_bounds__(256) void gemm1_kernel(
    const ushort* __restrict__ SA, const ushort* __restrict__ WcT,
    const float* __restrict__ s0, const int* __restrict__ cnt,
    const float* __restrict__ relb,
    float* __restrict__ symOut, __hip_bfloat16* __restrict__ symH)
{
    GEMM_PROLOGUE();
    __shared__ int clds[128][6];
    int row0 = blockIdx.y * 128, col0 = blockIdx.x * 128;
    gemm_core(SA, 1536, WcT, 1536, 1536, row0, col0, tid, Als, Bls, acc);
    __syncthreads();
    if (tid < 128) {
#pragma unroll
        for (int rr = 0; rr < 6; rr++) clds[tid][rr] = cnt[(row0 + tid) * 8 + rr];
    }
    __syncthreads();
    EPI_IDS();
#pragma unroll
    for (int nt = 0; nt < 4; nt++) {
        int col = col0 + wn * 64 + nt * 16 + l15;
        float rb[6];
#pragma unroll
        for (int rr = 0; rr < 6; rr++) rb[rr] = relb[rr * DD + col];
#pragma unroll
        for (int mt = 0; mt < 4; mt++)
#pragma unroll
            for (int v = 0; v < 4; v++) {
                int rowl = wm * 64 + mt * 16 + quad * 4 + v;
                int row = row0 + rowl;
                float x = acc[mt][nt][v] + s0[(size_t)row * DD + col];
#pragma unroll
                for (int rr = 0; rr < 6; rr++)
                    x += (float)clds[rowl][rr] * rb[rr];
                symOut[(size_t)row * DD + col] = x;
                symH[(size_t)row * DD + col] = __float2bfloat16(x);
            }
    }
}

// ----------------------------------------------------------------- gemm2 --
// [4096][256] @ Wbig^T. Col blocks 0..5: gelu + fused interp dot
// (atomicAdd into outI, which init_interp pre-loads with h2b).
// Col blocks 6..7: output projection -> out0.
__global__ __launch_bounds__(256) void gemm2_kernel(
    const ushort* __restrict__ symH, const ushort* __restrict__ WbT,
    const float* __restrict__ bbig, const float* __restrict__ h2W,
    float* __restrict__ out0, float* __restrict__ outI)
{
    GEMM_PROLOGUE();
    int row0 = blockIdx.y * 128, col0 = blockIdx.x * 128;
    gemm_core(symH, 256, WbT, 256, 256, row0, col0, tid, Als, Bls, acc);
    EPI_IDS();
    if (col0 >= 768) {
#pragma unroll
        for (int nt = 0; nt < 4; nt++) {
            int c = col0 + wn * 64 + nt * 16 + l15;
            float bb = bbig[c];
#pragma unroll
            for (int mt = 0; mt < 4; mt++)
#pragma unroll
                for (int v = 0; v < 4; v++) {
                    int row = row0 + wm * 64 + mt * 16 + quad * 4 + v;
                    out0[(size_t)row * DD + (c - 768)] = acc[mt][nt][v] + bb;
                }
        }
    } else {
        int head = col0 >> 8;                  // block fully inside one head
        float part[4][4];
#pragma unroll
        for (int mt = 0; mt < 4; mt++)
#pragma unroll
            for (int v = 0; v < 4; v++) part[mt][v] = 0.f;
#pragma unroll
        for (int nt = 0; nt < 4; nt++) {
            int c = col0 + wn * 64 + nt * 16 + l15;
            float bb = bbig[c];
            float w2 = h2W[c];                 // h2W[head*256 + (c&255)] == h2W[c]
#pragma unroll
            for (int mt = 0; mt < 4; mt++)
#pragma unroll
                for (int v = 0; v < 4; v++)
                    part[mt][v] += gelu_exact(acc[mt][nt][v] + bb) * w2;
        }
#pragma unroll
        for (int mt = 0; mt < 4; mt++)
#pragma unroll
            for (int v = 0; v < 4; v++) {
                float p = part[mt][v];
                p += __shfl_xor(p, 1); p += __shfl_xor(p, 2);
                p += __shfl_xor(p, 4); p += __shfl_xor(p, 8);
                if (l15 == 0) {
                    int row = row0 + wm * 64 + mt * 16 + quad * 4 + v;
                    atomicAdd(&outI[head * BNT + row], p);
                }
            }
    }
}

// ---------------------------------------------------------------- launch --
extern "C" void kernel_launch(void* const* d_in, const int* in_sizes, int n_in,
                              void* d_out, int out_size, void* d_ws, size_t ws_size,
                              hipStream_t stream)
{
    const int*   ids  = (const int*)d_in[0];
    const float* pos  = (const float*)d_in[1];
    const float* symt = (const float*)d_in[2];
    const float* layt = (const float*)d_in[3];
    const float* relW = (const float*)d_in[4];
    const float* relb = (const float*)d_in[5];
    const float* h1W  = (const float*)d_in[6];
    const float* h1b  = (const float*)d_in[7];
    const float* h2W  = (const float*)d_in[8];
    const float* h2b  = (const float*)d_in[9];
    const float* outW = (const float*)d_in[10];
    const float* outb = (const float*)d_in[11];
    float* out = (float*)d_out;
    float* ws  = (float*)d_ws;

    float* s0        = ws + OFF_S0;
    __hip_bfloat16* s0T  = (__hip_bfloat16*)(ws + OFF_S0T);
    ushort* maskp    = (ushort*)(ws + OFF_MASK);
    __hip_bfloat16* symH = (__hip_bfloat16*)(ws + OFF_SYMH);
    __hip_bfloat16* SA   = (__hip_bfloat16*)(ws + OFF_SA);
    int*    cntp     = (int*)(ws + OFF_CNT);
    __hip_bfloat16* WcT  = (__hip_bfloat16*)(ws + OFF_WCT);
    __hip_bfloat16* WbT  = (__hip_bfloat16*)(ws + OFF_WBT);
    float*  bbig     = ws + OFF_BB;

    prep_kernel<<<1536, 256, 0, stream>>>(relW, h1W, outW, h1b, outb, WcT, WbT, bbig);
    gather_kernel<<<4096, 256, 0, stream>>>(ids, symt, layt, s0);
    transpose_kernel<<<dim3(8, 4, 8), 256, 0, stream>>>(s0, s0T);
    classify_kernel<<<64, 256, 0, stream>>>(pos, maskp, cntp);
    init_interp_kernel<<<48, 256, 0, stream>>>(h2b, out + INTERP_OFF);
    agg_gemm<<<dim3(2, 4, 48), 256, 0, stream>>>(maskp, (const ushort*)s0T, SA);
    gemm1_kernel<<<dim3(2, 32), 256, 0, stream>>>((const ushort*)SA, (const ushort*)WcT,
                                                  s0, cntp, relb,
                                                  out + SYM_OFF, symH);
    gemm2_kernel<<<dim3(8, 32), 256, 0, stream>>>((const ushort*)symH, (const ushort*)WbT,
                                                  bbig, h2W,
                                                  out + OUT0_OFF, out + INTERP_OFF);
}